// Round 7
// baseline (144.925 us; speedup 1.0000x reference)
//
#include <hip/hip_runtime.h>

// IoULoss, C=4 over 16x1024x1024 preds(float,int-valued)/labels(int).
// R7: DMA-pipelined streaming. R1-R6 evidence: ~3.2 TB/s read ceiling on the
// VGPR-return load path regardless of VALU cost / grid / unroll / nt flags
// (Little's law: ~32 lines x 128B / ~780cy = 5.25 B/cyc/CU). global_load_lds
// demonstrated >= 52 B/cyc/CU staging in m97 GEMM => deeper outstanding queue.
// Structure: wave-private LDS ring (8 pairs x 2KB), global_load_lds width=16,
// fine-grained s_waitcnt vmcnt(14) steady state, NO barrier in the loop.

#define NCLS 4
#define NCNT (3 * NCLS)
#define QD 8            // ring depth in chunk-pairs
#define CHUNK 1024      // bytes per stream per chunk = 64 lanes x 16B
#define WPB 4           // waves per block (256 threads)

typedef float vf4 __attribute__((ext_vector_type(4)));
typedef int   vi4 __attribute__((ext_vector_type(4)));

typedef const __attribute__((address_space(1))) void glb_cv;
typedef __attribute__((address_space(3))) void lds_v;

// s_waitcnt imm (gfx9 encoding): vmcnt[3:0]|[15:14], expcnt[6:4], lgkmcnt[11:8]
#define WAITCNT_VM14 0x0F7E   // vmcnt<=14, expcnt/lgkmcnt = no-wait
#define WAITCNT_VM0  0x0F70   // vmcnt<=0
#define WAITCNT_LGKM0 0xC07F  // lgkmcnt<=0, vmcnt/expcnt = no-wait
#define CFENCE asm volatile("" ::: "memory")

__global__ __launch_bounds__(256) void iou_count_kernel(
    const float* __restrict__ preds,
    const int*   __restrict__ labels,
    unsigned int* __restrict__ partials,   // [NCNT][nblk], counter-major
    int n)
{
    __shared__ unsigned char smem[WPB * QD * 2 * CHUNK];   // 64 KB

    const int lane = threadIdx.x & 63;
    const int wid  = threadIdx.x >> 6;
    const int gw   = blockIdx.x * WPB + wid;   // global wave id
    const int W    = gridDim.x * WPB;          // total waves
    const int nch  = n >> 8;                   // 256 elems per chunk

    unsigned char* const base = smem + wid * (QD * 2 * CHUNK);

    unsigned int acc_i = 0, acc_p = 0, acc_l = 0;

    auto proc = [&](float pf, int lv) {
        const int      ip = (int)pf;
        const unsigned tp = 1u << (ip << 3);
        const unsigned tl = 1u << (lv << 3);
        acc_p += tp;
        acc_l += tl;
        acc_i += (ip == lv) ? tl : 0u;
    };

    auto issue = [&](int k) {
        const int slot = k & (QD - 1);
        const size_t c = (size_t)(gw + k * W) * 256 + lane * 4;
        __builtin_amdgcn_global_load_lds(
            (glb_cv*)(preds + c),
            (lds_v*)(base + slot * 2 * CHUNK), 16, 0, 0);
        __builtin_amdgcn_global_load_lds(
            (glb_cv*)(labels + c),
            (lds_v*)(base + slot * 2 * CHUNK + CHUNK), 16, 0, 0);
    };

    auto consume = [&](int k) {
        const int slot = k & (QD - 1);
        const vf4 p = *(const vf4*)(base + slot * 2 * CHUNK + lane * 16);
        const vi4 l = *(const vi4*)(base + slot * 2 * CHUNK + CHUNK + lane * 16);
        proc(p.x, l.x); proc(p.y, l.y); proc(p.z, l.z); proc(p.w, l.w);
    };

    // K chunks for this wave (K=32 at n=16.78M, nblk=512 -> 128 elems/lane,
    // byte-field max 128 < 255).
    const int K = (gw < nch) ? ((nch - gw - 1) / W + 1) : 0;

    const int pro = (K < QD) ? K : QD;
    for (int k = 0; k < pro; ++k) issue(k);

    // Steady state: wait only for the oldest pair (vmcnt<=14), consume, refill.
    int k = 0;
    for (; k < K - QD; ++k) {
        CFENCE; __builtin_amdgcn_s_waitcnt(WAITCNT_VM14); CFENCE;
        consume(k);
        // WAR guard: ds_reads of slot k must complete before DMA overwrites it.
        CFENCE; __builtin_amdgcn_s_waitcnt(WAITCNT_LGKM0); CFENCE;
        issue(k + QD);
    }
    // Drain.
    CFENCE; __builtin_amdgcn_s_waitcnt(WAITCNT_VM0); CFENCE;
    for (; k < K; ++k) consume(k);

    // Residual elements (n % 256) — block 0 / wave 0, plain loads.
    if (blockIdx.x == 0 && wid == 0) {
        for (int e = nch * 256 + lane; e < n; e += 64)
            proc(preds[e], labels[e]);
    }

    // Split packed-8 into packed-16 pairs (classes {0,2}/{1,3}), reduce.
    unsigned pk[6];
    pk[0] = acc_i & 0x00FF00FFu; pk[1] = (acc_i >> 8) & 0x00FF00FFu;
    pk[2] = acc_p & 0x00FF00FFu; pk[3] = (acc_p >> 8) & 0x00FF00FFu;
    pk[4] = acc_l & 0x00FF00FFu; pk[5] = (acc_l >> 8) & 0x00FF00FFu;

#pragma unroll
    for (int j = 0; j < 6; ++j) {
#pragma unroll
        for (int off = 32; off > 0; off >>= 1)
            pk[j] += __shfl_down(pk[j], off);
    }

    __shared__ unsigned int s[WPB][6];
    if (lane == 0) {
#pragma unroll
        for (int j = 0; j < 6; ++j) s[wid][j] = pk[j];
    }
    __syncthreads();

    if (threadIdx.x < 6) {
        const int j = threadIdx.x;
        const unsigned tot = s[0][j] + s[1][j] + s[2][j] + s[3][j];
        const int g = j >> 1, r = j & 1;
        partials[(g * NCLS + r)     * gridDim.x + blockIdx.x] = tot & 0xFFFFu;
        partials[(g * NCLS + r + 2) * gridDim.x + blockIdx.x] = tot >> 16;
    }
}

// One block, 12 waves: wave w sums counter row w; threads 0..3 finalize.
__global__ __launch_bounds__(768) void iou_reduce_kernel(
    const unsigned int* __restrict__ partials,
    float* __restrict__ out,
    int nblk)
{
    __shared__ unsigned int tot[NCNT];
    const int w    = threadIdx.x >> 6;
    const int lane = threadIdx.x & 63;

    if (w < NCNT) {
        unsigned int sum = 0;
        const unsigned int* row = partials + (size_t)w * nblk;
        for (int i = lane; i < nblk; i += 64)
            sum += row[i];
#pragma unroll
        for (int off = 32; off > 0; off >>= 1)
            sum += __shfl_down(sum, off);
        if (lane == 0) tot[w] = sum;
    }
    __syncthreads();

    if (threadIdx.x < NCLS) {
        const int c = threadIdx.x;
        const float inter = (float)tot[c];
        const float uni   = (float)tot[NCLS + c] + (float)tot[2 * NCLS + c]
                            - (float)tot[c];
        const float iou   = (uni == 0.0f) ? 1.0f : (inter / uni);
        out[c] = 1.0f - 100.0f * iou;
    }
}

extern "C" void kernel_launch(void* const* d_in, const int* in_sizes, int n_in,
                              void* d_out, int out_size, void* d_ws, size_t ws_size,
                              hipStream_t stream) {
    const float* preds  = (const float*)d_in[0];
    const int*   labels = (const int*)d_in[1];
    unsigned int* partials = (unsigned int*)d_ws;
    float* out = (float*)d_out;

    const int n = in_sizes[0];       // 16*1024*1024

    // 512 blocks x 4 waves = 2048 waves; 64KB LDS -> 2 blocks/CU.
    // K = 32 chunks/wave keeps packed byte-fields < 255.
    int nblk = 512;
    const int cap = (int)(ws_size / (NCNT * sizeof(unsigned int)));
    if (cap < nblk) nblk = cap;
    if (nblk < 1) nblk = 1;

    iou_count_kernel<<<nblk, 256, 0, stream>>>(preds, labels, partials, n);
    iou_reduce_kernel<<<1, 768, 0, stream>>>(partials, out, nblk);
}